// Round 8
// baseline (175.121 us; speedup 1.0000x reference)
//
#include <hip/hip_runtime.h>
#include <hip/hip_bf16.h>

typedef unsigned short u16;
typedef __attribute__((ext_vector_type(8))) __bf16 bf16x8;
typedef __attribute__((ext_vector_type(4))) __bf16 bf16x4;
typedef __attribute__((ext_vector_type(4))) float f32x4;

#define LOG2E 1.44269504f

#if __has_builtin(__builtin_amdgcn_exp2f)
#define EXP2F(x) __builtin_amdgcn_exp2f(x)
#else
#define EXP2F(x) __expf((x) * 0.69314718f)
#endif

#define GLL16(gptr, lptr) \
  __builtin_amdgcn_global_load_lds((__attribute__((address_space(1))) void*)(gptr), \
                                   (__attribute__((address_space(3))) void*)(lptr), 16, 0, 0)

static __device__ __forceinline__ u16 f2bf(float f) {
  union { float f; unsigned u; } v; v.f = f;
  unsigned r = (v.u + 0x7FFFu + ((v.u >> 16) & 1u)) >> 16;
  return (u16)r;
}

// ---------------- fused fp32 -> bf16 convert (5 tensors, 1 launch) ----------------
__global__ __launch_bounds__(256) void cvt_all(
    const float* __restrict__ q, const float* __restrict__ k, const float* __restrict__ v,
    const float* __restrict__ w1, const float* __restrict__ w2,
    u16* __restrict__ xq, u16* __restrict__ xk, u16* __restrict__ xv,
    u16* __restrict__ wq, u16* __restrict__ wp) {
  const int b = blockIdx.x;
  const float* src; u16* dst; int off;
  if (b < 4096)       { src = q;  dst = xq; off = b; }
  else if (b < 8192)  { src = k;  dst = xk; off = b - 4096; }
  else if (b < 12288) { src = v;  dst = xv; off = b - 8192; }
  else if (b < 15360) { src = w1; dst = wq; off = b - 12288; }
  else                { src = w2; dst = wp; off = b - 15360; }
  const int i = off * 256 + threadIdx.x;
  float4 vv = ((const float4*)src)[i];
  ushort4 o;
  o.x = f2bf(vv.x); o.y = f2bf(vv.y); o.z = f2bf(vv.z); o.w = f2bf(vv.w);
  ((ushort4*)dst)[i] = o;
}

// ---------------- QKV projection GEMM ----------------
// C[s][f] = sum_e X[s][e] * W[f][e] + bias[f]. Q output pre-scaled by 0.125*log2e.
__global__ __launch_bounds__(256, 2) void qkv_gemm(
    const u16* __restrict__ xq, const u16* __restrict__ xk, const u16* __restrict__ xv,
    const u16* __restrict__ wbf, const float* __restrict__ bias,
    u16* __restrict__ qout, u16* __restrict__ kout, u16* __restrict__ vtout) {
  __shared__ u16 Al[128 * 32];
  __shared__ u16 Bl[128 * 32];
  const int tid = threadIdx.x;
  const int lane = tid & 63;
  const int w = tid >> 6;
  const int wr = w >> 1, wc = w & 1;
  const int nb = blockIdx.x, mb = blockIdx.y;
  const int row0 = mb * 128;
  const int ncol0 = nb * 128;
  const int which = nb >> 3;  // 0:Q 1:K 2:V
  const u16* A = (which == 0) ? xq : (which == 1) ? xk : xv;
  const u16* Bw = wbf + (size_t)ncol0 * 1024;

  f32x4 acc[4][4];
  f32x4 zero = {0.f, 0.f, 0.f, 0.f};
#pragma unroll
  for (int i = 0; i < 4; i++)
#pragma unroll
    for (int j = 0; j < 4; j++) acc[i][j] = zero;

  const int srow = w * 16 + (lane >> 2);
  const int scol = (lane & 3) * 8;

  for (int k0 = 0; k0 < 1024; k0 += 32) {
#pragma unroll
    for (int p = 0; p < 2; p++) {
      const u16* ga = A + (size_t)(row0 + p * 64 + srow) * 1024 + k0 + scol;
      GLL16(ga, &Al[(p * 64 + w * 16) * 32]);
      const u16* gb = Bw + (size_t)(p * 64 + srow) * 1024 + k0 + scol;
      GLL16(gb, &Bl[(p * 64 + w * 16) * 32]);
    }
    __syncthreads();
    bf16x8 af[4], bfr[4];
#pragma unroll
    for (int mi = 0; mi < 4; mi++)
      af[mi] = *(const bf16x8*)&Al[(wr * 64 + mi * 16 + (lane & 15)) * 32 + (lane >> 4) * 8];
#pragma unroll
    for (int ni = 0; ni < 4; ni++)
      bfr[ni] = *(const bf16x8*)&Bl[(wc * 64 + ni * 16 + (lane & 15)) * 32 + (lane >> 4) * 8];
#pragma unroll
    for (int mi = 0; mi < 4; mi++)
#pragma unroll
      for (int ni = 0; ni < 4; ni++)
        acc[mi][ni] = __builtin_amdgcn_mfma_f32_16x16x32_bf16(af[mi], bfr[ni], acc[mi][ni], 0, 0, 0);
    __syncthreads();
  }

#pragma unroll
  for (int mi = 0; mi < 4; mi++) {
    const int rb = row0 + wr * 64 + mi * 16 + (lane >> 4) * 4;
#pragma unroll
    for (int ni = 0; ni < 4; ni++) {
      const int c = ncol0 + wc * 64 + ni * 16 + (lane & 15);
      const float bs = bias[c];
      const float sc = (which == 0) ? (0.125f * LOG2E) : 1.0f;
      const int fm = c & 1023;
      const int h = fm >> 6, d = fm & 63;
#pragma unroll
      for (int r = 0; r < 4; r++) {
        const int rr = rb + r;
        const int b = rr >> 11, s = rr & 2047;
        const u16 val = f2bf((acc[mi][ni][r] + bs) * sc);
        if (which == 0)
          qout[(((size_t)(b * 16 + h)) * 2048 + s) * 64 + d] = val;
        else if (which == 1)
          kout[(((size_t)(b * 16 + h)) * 2048 + s) * 64 + d] = val;
        else
          vtout[(((size_t)(b * 16 + h)) * 64 + d) * 2048 + s] = val;
      }
    }
  }
}

// ---------------- flash attention ----------------
// grid (bh=32, qtile=16), block 512 (8 waves x 16 q = 128 q-rows/block).
// KV processed in PAIRS of 64-tiles per iteration: 4 LDS buffer sets, ONE
// barrier per pair, QK/softmax/PV of both tiles issued together for 2x ILP
// (the kernel is dependency-latency-bound at 2 blocks/CU, not pipe-bound).
// P never goes to LDS (pi-permuted V; PV B-operand = QK C-layout registers).
// LDS (64 KB): K pair-even [0,16384) {tileA 0, tileB 8192}, pair-odd [16384,32768);
//              V at 32768 + same.

#define QK4(SS0, SS1, SS2, SS3, KOFF, MC)                                          \
  {                                                                                \
    bf16x8 a_, b_;                                                                 \
    a_ = *(const bf16x8*)(ldsb + Kr0 + 0 + (KOFF));                                \
    b_ = *(const bf16x8*)(ldsb + Kr1 + 0 + (KOFF));                                \
    SS0 = __builtin_amdgcn_mfma_f32_16x16x32_bf16(a_, q0, MC[0], 0, 0, 0);         \
    SS0 = __builtin_amdgcn_mfma_f32_16x16x32_bf16(b_, q1, SS0, 0, 0, 0);           \
    a_ = *(const bf16x8*)(ldsb + Kr0 + 2048 + (KOFF));                             \
    b_ = *(const bf16x8*)(ldsb + Kr1 + 2048 + (KOFF));                             \
    SS1 = __builtin_amdgcn_mfma_f32_16x16x32_bf16(a_, q0, MC[1], 0, 0, 0);         \
    SS1 = __builtin_amdgcn_mfma_f32_16x16x32_bf16(b_, q1, SS1, 0, 0, 0);           \
    a_ = *(const bf16x8*)(ldsb + Kr0 + 4096 + (KOFF));                             \
    b_ = *(const bf16x8*)(ldsb + Kr1 + 4096 + (KOFF));                             \
    SS2 = __builtin_amdgcn_mfma_f32_16x16x32_bf16(a_, q0, MC[2], 0, 0, 0);         \
    SS2 = __builtin_amdgcn_mfma_f32_16x16x32_bf16(b_, q1, SS2, 0, 0, 0);           \
    a_ = *(const bf16x8*)(ldsb + Kr0 + 6144 + (KOFF));                             \
    b_ = *(const bf16x8*)(ldsb + Kr1 + 6144 + (KOFF));                             \
    SS3 = __builtin_amdgcn_mfma_f32_16x16x32_bf16(a_, q0, MC[3], 0, 0, 0);         \
    SS3 = __builtin_amdgcn_mfma_f32_16x16x32_bf16(b_, q1, SS3, 0, 0, 0);           \
  }

#define PV8(PA0, PA1, VOFF)                                                        \
  {                                                                                \
    bf16x8 v0_, v1_;                                                               \
    v0_ = *(const bf16x8*)(ldsb + Kr0 + 0 + (VOFF));                               \
    v1_ = *(const bf16x8*)(ldsb + Kr1 + 0 + (VOFF));                               \
    ctx[0] = __builtin_amdgcn_mfma_f32_16x16x32_bf16(v0_, PA0, ctx[0], 0, 0, 0);   \
    ctx[0] = __builtin_amdgcn_mfma_f32_16x16x32_bf16(v1_, PA1, ctx[0], 0, 0, 0);   \
    v0_ = *(const bf16x8*)(ldsb + Kr0 + 2048 + (VOFF));                            \
    v1_ = *(const bf16x8*)(ldsb + Kr1 + 2048 + (VOFF));                            \
    ctx[1] = __builtin_amdgcn_mfma_f32_16x16x32_bf16(v0_, PA0, ctx[1], 0, 0, 0);   \
    ctx[1] = __builtin_amdgcn_mfma_f32_16x16x32_bf16(v1_, PA1, ctx[1], 0, 0, 0);   \
    v0_ = *(const bf16x8*)(ldsb + Kr0 + 4096 + (VOFF));                            \
    v1_ = *(const bf16x8*)(ldsb + Kr1 + 4096 + (VOFF));                            \
    ctx[2] = __builtin_amdgcn_mfma_f32_16x16x32_bf16(v0_, PA0, ctx[2], 0, 0, 0);   \
    ctx[2] = __builtin_amdgcn_mfma_f32_16x16x32_bf16(v1_, PA1, ctx[2], 0, 0, 0);   \
    v0_ = *(const bf16x8*)(ldsb + Kr0 + 6144 + (VOFF));                            \
    v1_ = *(const bf16x8*)(ldsb + Kr1 + 6144 + (VOFF));                            \
    ctx[3] = __builtin_amdgcn_mfma_f32_16x16x32_bf16(v0_, PA0, ctx[3], 0, 0, 0);   \
    ctx[3] = __builtin_amdgcn_mfma_f32_16x16x32_bf16(v1_, PA1, ctx[3], 0, 0, 0);   \
  }

#define EXPV(SS)                                                                   \
  SS[0] = EXP2F(SS[0] - m); SS[1] = EXP2F(SS[1] - m);                              \
  SS[2] = EXP2F(SS[2] - m); SS[3] = EXP2F(SS[3] - m);

__global__ __launch_bounds__(512, 4) void attn_fwd(
    const u16* __restrict__ qbf, const u16* __restrict__ kbf, const u16* __restrict__ vtbf,
    const float* __restrict__ mask, u16* __restrict__ ctxout) {
  __shared__ u16 lds[32768];  // 64 KB
  char* ldsb = (char*)lds;
  const int tid = threadIdx.x, lane = tid & 63, w = tid >> 6;
  const int qL = lane & 15, g = lane >> 4;
  const int x = (qL & 7) << 4;
  const int bh = blockIdx.x, qt = blockIdx.y;
  const int qbase = qt * 128;
  const size_t hbase = (size_t)bh * 2048 * 64;
  const int qrow = qbase + w * 16 + qL;

  // loop-invariant LDS byte addresses
  const int Kr0 = qL * 128 + ((g * 16) ^ x);
  const int Kr1 = qL * 128 + ((g * 16 + 64) ^ x);
  const int srow = tid >> 3;           // 0..63
  const int scol = (tid & 7) * 8;
  const int S0 = srow * 128 + (((tid & 7) * 16) ^ ((srow & 7) << 4));
  // V staging: float4 (t=8a..8a+7) splits into 2x8B at pi-permuted offsets
  const int a_ = tid & 7;
  const int vW1 = ((a_ >> 2) << 6) + (((2 * a_) & 3) << 4) + (((a_ >> 1) & 1) << 3);
  const int vW2 = ((a_ >> 2) << 6) + (((2 * a_ + 1) & 3) << 4) + (((a_ >> 1) & 1) << 3);
  const int sxr = (srow & 7) << 4;
  const int VS0a = srow * 128 + (vW1 ^ sxr);
  const int VS0b = srow * 128 + (vW2 ^ sxr);

  // Q fragments (pre-scaled by 0.125*log2e in qkv epilogue)
  bf16x8 q0 = *(const bf16x8*)&qbf[hbase + (size_t)qrow * 64 + g * 8];
  bf16x8 q1 = *(const bf16x8*)&qbf[hbase + (size_t)qrow * 64 + 32 + g * 8];

  // prologue: pair 0 (tiles 0,1) -> even bufs; pair 1 (tiles 2,3) -> regs
  float4 kr0, kr1, vr0, vr1;
  kr0 = *(const float4*)&kbf[hbase + (size_t)srow * 64 + scol];
  kr1 = *(const float4*)&kbf[hbase + (size_t)(64 + srow) * 64 + scol];
  vr0 = *(const float4*)&vtbf[hbase + (size_t)srow * 2048 + scol];
  vr1 = *(const float4*)&vtbf[hbase + (size_t)srow * 2048 + 64 + scol];
  *(float4*)(ldsb + S0) = kr0;
  *(float4*)(ldsb + 8192 + S0) = kr1;
  *(float2*)(ldsb + 32768 + VS0a) = make_float2(vr0.x, vr0.y);
  *(float2*)(ldsb + 32768 + VS0b) = make_float2(vr0.z, vr0.w);
  *(float2*)(ldsb + 40960 + VS0a) = make_float2(vr1.x, vr1.y);
  *(float2*)(ldsb + 40960 + VS0b) = make_float2(vr1.z, vr1.w);
  kr0 = *(const float4*)&kbf[hbase + (size_t)(128 + srow) * 64 + scol];
  kr1 = *(const float4*)&kbf[hbase + (size_t)(192 + srow) * 64 + scol];
  vr0 = *(const float4*)&vtbf[hbase + (size_t)srow * 2048 + 128 + scol];
  vr1 = *(const float4*)&vtbf[hbase + (size_t)srow * 2048 + 192 + scol];

  // global stream pointers (pair 2 = tiles 4,5 onward)
  const u16* kp = kbf + hbase + (size_t)(256 + srow) * 64 + scol;
  const u16* vp = vtbf + hbase + (size_t)srow * 2048 + 256 + scol;
  const float* mp = mask + (size_t)qrow * 2048 + g * 4;

  f32x4 mA[4], mB[4];
#pragma unroll
  for (int tb = 0; tb < 4; tb++) {
    mA[tb] = (*(const f32x4*)(mp + tb * 16)) * LOG2E;
    mB[tb] = (*(const f32x4*)(mp + 64 + tb * 16)) * LOG2E;
  }

  float m = 0.f, lsum = 0.f;  // m=0 init safe: defer-max picks up
  f32x4 ctx[4];
  f32x4 zero = {0.f, 0.f, 0.f, 0.f};
#pragma unroll
  for (int db = 0; db < 4; db++) ctx[db] = zero;

  __syncthreads();

  for (int i = 0; i < 16; ++i) {
    const int cb = (i & 1) << 14;      // compute-pair byte offset
    const int sb = 16384 - cb;         // stage-pair byte offset
    f32x4 sA0, sA1, sA2, sA3, sB0, sB1, sB2, sB3;

    // QK of both tiles (independent -> deep ILP)
    __builtin_amdgcn_s_setprio(1);
    QK4(sA0, sA1, sA2, sA3, cb, mA)
    QK4(sB0, sB1, sB2, sB3, cb + 8192, mB)
    __builtin_amdgcn_s_setprio(0);

    // stage pair i+1 (regs from last iter); overlap with softmax below
    if (i < 15) {
      *(float4*)(ldsb + sb + S0) = kr0;
      *(float4*)(ldsb + sb + 8192 + S0) = kr1;
      *(float2*)(ldsb + 32768 + sb + VS0a) = make_float2(vr0.x, vr0.y);
      *(float2*)(ldsb + 32768 + sb + VS0b) = make_float2(vr0.z, vr0.w);
      *(float2*)(ldsb + 40960 + sb + VS0a) = make_float2(vr1.x, vr1.y);
      *(float2*)(ldsb + 40960 + sb + VS0b) = make_float2(vr1.z, vr1.w);
    }
    if (i < 14) {                       // load pair i+2
      kr0 = *(const float4*)kp;
      kr1 = *(const float4*)(kp + 4096);
      vr0 = *(const float4*)vp;
      vr1 = *(const float4*)(vp + 64);
      kp += 8192; vp += 128;
    }
    if (i < 15) {                       // masks for pair i+1
#pragma unroll
      for (int tb = 0; tb < 4; tb++) {
        mA[tb] = (*(const f32x4*)(mp + 128 + tb * 16)) * LOG2E;
        mB[tb] = (*(const f32x4*)(mp + 192 + tb * 16)) * LOG2E;
      }
    }
    mp += 128;

    // combined softmax over 128 t-cols (one shfl-pair, one rescale check)
    float pm = fmaxf(
        fmaxf(fmaxf(fmaxf(fmaxf(sA0[0], sA0[1]), fmaxf(sA0[2], sA0[3])),
                    fmaxf(fmaxf(sA1[0], sA1[1]), fmaxf(sA1[2], sA1[3]))),
              fmaxf(fmaxf(fmaxf(sA2[0], sA2[1]), fmaxf(sA2[2], sA2[3])),
                    fmaxf(fmaxf(sA3[0], sA3[1]), fmaxf(sA3[2], sA3[3])))),
        fmaxf(fmaxf(fmaxf(fmaxf(sB0[0], sB0[1]), fmaxf(sB0[2], sB0[3])),
                    fmaxf(fmaxf(sB1[0], sB1[1]), fmaxf(sB1[2], sB1[3]))),
              fmaxf(fmaxf(fmaxf(sB2[0], sB2[1]), fmaxf(sB2[2], sB2[3])),
                    fmaxf(fmaxf(sB3[0], sB3[1]), fmaxf(sB3[2], sB3[3])))));
    // speculative exp with current m; shfl max-reduce overlaps
    EXPV(sA0) EXPV(sA1) EXPV(sA2) EXPV(sA3)
    EXPV(sB0) EXPV(sB1) EXPV(sB2) EXPV(sB3)
    float ps = (((sA0[0] + sA0[1]) + (sA0[2] + sA0[3])) +
                ((sA1[0] + sA1[1]) + (sA1[2] + sA1[3]))) +
               (((sA2[0] + sA2[1]) + (sA2[2] + sA2[3])) +
                ((sA3[0] + sA3[1]) + (sA3[2] + sA3[3]))) +
               (((sB0[0] + sB0[1]) + (sB0[2] + sB0[3])) +
                ((sB1[0] + sB1[1]) + (sB1[2] + sB1[3]))) +
               (((sB2[0] + sB2[1]) + (sB2[2] + sB2[3])) +
                ((sB3[0] + sB3[1]) + (sB3[2] + sB3[3])));
    pm = fmaxf(pm, __shfl_xor(pm, 16));
    pm = fmaxf(pm, __shfl_xor(pm, 32));
    if (__any(pm > m + 8.0f)) {  // rare: fix speculation exactly
      const float mn = fmaxf(m, pm);
      const float al = EXP2F(m - mn);
      m = mn; lsum *= al; ps *= al;
      sA0 *= al; sA1 *= al; sA2 *= al; sA3 *= al;
      sB0 *= al; sB1 *= al; sB2 *= al; sB3 *= al;
      ctx[0] *= al; ctx[1] *= al; ctx[2] *= al; ctx[3] *= al;
    }
    lsum += ps;

    // pack P into PV B-operands (pi-matched; no LDS round-trip)
    bf16x8 paA0, paA1, paB0, paB1;
    paA0[0] = (__bf16)sA0[0]; paA0[1] = (__bf16)sA0[1];
    paA0[2] = (__bf16)sA0[2]; paA0[3] = (__bf16)sA0[3];
    paA0[4] = (__bf16)sA1[0]; paA0[5] = (__bf16)sA1[1];
    paA0[6] = (__bf16)sA1[2]; paA0[7] = (__bf16)sA1[3];
    paA1[0] = (__bf16)sA2[0]; paA1[1] = (__bf16)sA2[1];
    paA1[2] = (__bf16)sA2[2]; paA1[3] = (__bf16)sA2[3];
    paA1[4] = (__bf16)sA3[0]; paA1[5] = (__bf16)sA3[1];
    paA1[6] = (__bf16)sA3[2]; paA1[7] = (__bf16)sA3[3];
    paB0[0] = (__bf16)sB0[0]; paB0[1] = (__bf16)sB0[1];
    paB0[2] = (__bf16)sB0[2]; paB0[3] = (__bf16)sB0[3];
    paB0[4] = (__bf16)sB1[0]; paB0[5] = (__bf16)sB1[1];
    paB0[6] = (__bf16)sB1[2]; paB0[7] = (__bf16)sB1[3];
    paB1[0] = (__bf16)sB2[0]; paB1[1] = (__bf16)sB2[1];
    paB1[2] = (__bf16)sB2[2]; paB1[3] = (__bf16)sB2[3];
    paB1[4] = (__bf16)sB3[0]; paB1[5] = (__bf16)sB3[1];
    paB1[6] = (__bf16)sB3[2]; paB1[7] = (__bf16)sB3[3];

    // PV of both tiles
    __builtin_amdgcn_s_setprio(1);
    PV8(paA0, paA1, 32768 + cb)
    PV8(paB0, paB1, 40960 + cb)
    __builtin_amdgcn_s_setprio(0);

    __syncthreads();
  }

  // finalize: reduce per-lane partial lsum across the 4 g-lane groups
  lsum += __shfl_xor(lsum, 16);
  lsum += __shfl_xor(lsum, 32);
  const float inv = 1.0f / lsum;
  const int b = bh >> 4, h = bh & 15;
  u16* orow = ctxout + (size_t)(b * 2048 + qrow) * 1024 + h * 64;
#pragma unroll
  for (int db = 0; db < 4; db++) {
    bf16x4 o;
    o[0] = (__bf16)(ctx[db][0] * inv);
    o[1] = (__bf16)(ctx[db][1] * inv);
    o[2] = (__bf16)(ctx[db][2] * inv);
    o[3] = (__bf16)(ctx[db][3] * inv);
    *(bf16x4*)&orow[db * 16 + g * 4] = o;
  }
}

// ---------------- output projection GEMM ----------------
__global__ __launch_bounds__(256, 2) void proj_gemm(
    const u16* __restrict__ ctx, const u16* __restrict__ wbf,
    const float* __restrict__ bias, float* __restrict__ out) {
  __shared__ u16 Al[128 * 32];
  __shared__ u16 Bl[128 * 32];
  const int tid = threadIdx.x;
  const int lane = tid & 63;
  const int w = tid >> 6;
  const int wr = w >> 1, wc = w & 1;
  const int nb = blockIdx.x, mb = blockIdx.y;
  const int row0 = mb * 128;
  const int ncol0 = nb * 128;
  const u16* Bw = wbf + (size_t)ncol0 * 1024;

  f32x4 acc[4][4];
  f32x4 zero = {0.f, 0.f, 0.f, 0.f};
#pragma unroll
  for (int i = 0; i < 4; i++)
#pragma unroll
    for (int j = 0; j < 4; j++) acc[i][j] = zero;

  const int srow = w * 16 + (lane >> 2);
  const int scol = (lane & 3) * 8;

  for (int k0 = 0; k0 < 1024; k0 += 32) {
#pragma unroll
    for (int p = 0; p < 2; p++) {
      const u16* ga = ctx + (size_t)(row0 + p * 64 + srow) * 1024 + k0 + scol;
      GLL16(ga, &Al[(p * 64 + w * 16) * 32]);
      const u16* gb = Bw + (size_t)(p * 64 + srow) * 1024 + k0 + scol;
      GLL16(gb, &Bl[(p * 64 + w * 16) * 32]);
    }
    __syncthreads();
    bf16x8 af[4], bfr[4];
#pragma unroll
    for (int mi = 0; mi < 4; mi++)
      af[mi] = *(const bf16x8*)&Al[(wr * 64 + mi * 16 + (lane & 15)) * 32 + (lane >> 4) * 8];
#pragma unroll
    for (int ni = 0; ni < 4; ni++)
      bfr[ni] = *(const bf16x8*)&Bl[(wc * 64 + ni * 16 + (lane & 15)) * 32 + (lane >> 4) * 8];
#pragma unroll
    for (int mi = 0; mi < 4; mi++)
#pragma unroll
      for (int ni = 0; ni < 4; ni++)
        acc[mi][ni] = __builtin_amdgcn_mfma_f32_16x16x32_bf16(af[mi], bfr[ni], acc[mi][ni], 0, 0, 0);
    __syncthreads();
  }

#pragma unroll
  for (int mi = 0; mi < 4; mi++) {
    const int rb = row0 + wr * 64 + mi * 16 + (lane >> 4) * 4;
#pragma unroll
    for (int ni = 0; ni < 4; ni++) {
      const int c = ncol0 + wc * 64 + ni * 16 + (lane & 15);
      const float bs = bias[c];
#pragma unroll
      for (int r = 0; r < 4; r++)
        out[(size_t)(rb + r) * 1024 + c] = acc[mi][ni][r] + bs;
    }
  }
}

// ---------------- launch ----------------
extern "C" void kernel_launch(void* const* d_in, const int* in_sizes, int n_in,
                              void* d_out, int out_size, void* d_ws, size_t ws_size,
                              hipStream_t stream) {
  const float* query = (const float*)d_in[0];
  const float* key   = (const float*)d_in[1];
  const float* value = (const float*)d_in[2];
  const float* qkvw  = (const float*)d_in[3];
  const float* qkvb  = (const float*)d_in[4];
  const float* projw = (const float*)d_in[5];
  const float* projb = (const float*)d_in[6];
  const float* mask  = (const float*)d_in[7];

  char* ws = (char*)d_ws;
  u16* xq    = (u16*)(ws + 0);          // 8 MiB  (later: ctx)
  u16* xk    = (u16*)(ws + 8388608);    // 8 MiB
  u16* xv    = (u16*)(ws + 16777216);   // 8 MiB
  u16* wqkv  = (u16*)(ws + 25165824);   // 6 MiB
  u16* wproj = (u16*)(ws + 31457280);   // 2 MiB
  u16* qb    = (u16*)(ws + 33554432);   // 8 MiB  [B,H,S,D] (pre-scaled)
  u16* kb    = (u16*)(ws + 41943040);   // 8 MiB  [B,H,S,D]
  u16* vt    = (u16*)(ws + 50331648);   // 8 MiB  [B,H,D,S]
  u16* cx    = xq;                      // ctx bf16, aliases xq

  cvt_all<<<16384, 256, 0, stream>>>(query, key, value, qkvw, projw, xq, xk, xv, wqkv, wproj);
  qkv_gemm<<<dim3(24, 32), 256, 0, stream>>>(xq, xk, xv, wqkv, qkvb, qb, kb, vt);
  attn_fwd<<<dim3(32, 16), 512, 0, stream>>>(qb, kb, vt, mask, cx);
  proj_gemm<<<dim3(8, 32), 256, 0, stream>>>(cx, wproj, projb, (float*)d_out);
}

// Round 9
// 169.178 us; speedup vs baseline: 1.0351x; 1.0351x over previous
//
#include <hip/hip_runtime.h>
#include <hip/hip_bf16.h>

typedef unsigned short u16;
typedef __attribute__((ext_vector_type(8))) __bf16 bf16x8;
typedef __attribute__((ext_vector_type(4))) __bf16 bf16x4;
typedef __attribute__((ext_vector_type(4))) float f32x4;
typedef __attribute__((ext_vector_type(16))) float f32x16;

#define LOG2E 1.44269504f

#if __has_builtin(__builtin_amdgcn_exp2f)
#define EXP2F(x) __builtin_amdgcn_exp2f(x)
#else
#define EXP2F(x) __expf((x) * 0.69314718f)
#endif

#define GLL16(gptr, lptr) \
  __builtin_amdgcn_global_load_lds((__attribute__((address_space(1))) void*)(gptr), \
                                   (__attribute__((address_space(3))) void*)(lptr), 16, 0, 0)

static __device__ __forceinline__ u16 f2bf(float f) {
  union { float f; unsigned u; } v; v.f = f;
  unsigned r = (v.u + 0x7FFFu + ((v.u >> 16) & 1u)) >> 16;
  return (u16)r;
}

// ---------------- fused fp32 -> bf16 convert (5 tensors, 1 launch) ----------------
__global__ __launch_bounds__(256) void cvt_all(
    const float* __restrict__ q, const float* __restrict__ k, const float* __restrict__ v,
    const float* __restrict__ w1, const float* __restrict__ w2,
    u16* __restrict__ xq, u16* __restrict__ xk, u16* __restrict__ xv,
    u16* __restrict__ wq, u16* __restrict__ wp) {
  const int b = blockIdx.x;
  const float* src; u16* dst; int off;
  if (b < 4096)       { src = q;  dst = xq; off = b; }
  else if (b < 8192)  { src = k;  dst = xk; off = b - 4096; }
  else if (b < 12288) { src = v;  dst = xv; off = b - 8192; }
  else if (b < 15360) { src = w1; dst = wq; off = b - 12288; }
  else                { src = w2; dst = wp; off = b - 15360; }
  const int i = off * 256 + threadIdx.x;
  float4 vv = ((const float4*)src)[i];
  ushort4 o;
  o.x = f2bf(vv.x); o.y = f2bf(vv.y); o.z = f2bf(vv.z); o.w = f2bf(vv.w);
  ((ushort4*)dst)[i] = o;
}

// ---------------- QKV projection GEMM ----------------
__global__ __launch_bounds__(256, 2) void qkv_gemm(
    const u16* __restrict__ xq, const u16* __restrict__ xk, const u16* __restrict__ xv,
    const u16* __restrict__ wbf, const float* __restrict__ bias,
    u16* __restrict__ qout, u16* __restrict__ kout, u16* __restrict__ vtout) {
  __shared__ u16 Al[128 * 32];
  __shared__ u16 Bl[128 * 32];
  const int tid = threadIdx.x;
  const int lane = tid & 63;
  const int w = tid >> 6;
  const int wr = w >> 1, wc = w & 1;
  const int nb = blockIdx.x, mb = blockIdx.y;
  const int row0 = mb * 128;
  const int ncol0 = nb * 128;
  const int which = nb >> 3;  // 0:Q 1:K 2:V
  const u16* A = (which == 0) ? xq : (which == 1) ? xk : xv;
  const u16* Bw = wbf + (size_t)ncol0 * 1024;

  f32x4 acc[4][4];
  f32x4 zero = {0.f, 0.f, 0.f, 0.f};
#pragma unroll
  for (int i = 0; i < 4; i++)
#pragma unroll
    for (int j = 0; j < 4; j++) acc[i][j] = zero;

  const int srow = w * 16 + (lane >> 2);
  const int scol = (lane & 3) * 8;

  for (int k0 = 0; k0 < 1024; k0 += 32) {
#pragma unroll
    for (int p = 0; p < 2; p++) {
      const u16* ga = A + (size_t)(row0 + p * 64 + srow) * 1024 + k0 + scol;
      GLL16(ga, &Al[(p * 64 + w * 16) * 32]);
      const u16* gb = Bw + (size_t)(p * 64 + srow) * 1024 + k0 + scol;
      GLL16(gb, &Bl[(p * 64 + w * 16) * 32]);
    }
    __syncthreads();
    bf16x8 af[4], bfr[4];
#pragma unroll
    for (int mi = 0; mi < 4; mi++)
      af[mi] = *(const bf16x8*)&Al[(wr * 64 + mi * 16 + (lane & 15)) * 32 + (lane >> 4) * 8];
#pragma unroll
    for (int ni = 0; ni < 4; ni++)
      bfr[ni] = *(const bf16x8*)&Bl[(wc * 64 + ni * 16 + (lane & 15)) * 32 + (lane >> 4) * 8];
#pragma unroll
    for (int mi = 0; mi < 4; mi++)
#pragma unroll
      for (int ni = 0; ni < 4; ni++)
        acc[mi][ni] = __builtin_amdgcn_mfma_f32_16x16x32_bf16(af[mi], bfr[ni], acc[mi][ni], 0, 0, 0);
    __syncthreads();
  }

#pragma unroll
  for (int mi = 0; mi < 4; mi++) {
    const int rb = row0 + wr * 64 + mi * 16 + (lane >> 4) * 4;
#pragma unroll
    for (int ni = 0; ni < 4; ni++) {
      const int c = ncol0 + wc * 64 + ni * 16 + (lane & 15);
      const float bs = bias[c];
      const float sc = (which == 0) ? (0.125f * LOG2E) : 1.0f;
      const int fm = c & 1023;
      const int h = fm >> 6, d = fm & 63;
#pragma unroll
      for (int r = 0; r < 4; r++) {
        const int rr = rb + r;
        const int b = rr >> 11, s = rr & 2047;
        const u16 val = f2bf((acc[mi][ni][r] + bs) * sc);
        if (which == 0)
          qout[(((size_t)(b * 16 + h)) * 2048 + s) * 64 + d] = val;
        else if (which == 1)
          kout[(((size_t)(b * 16 + h)) * 2048 + s) * 64 + d] = val;
        else
          vtout[(((size_t)(b * 16 + h)) * 64 + d) * 2048 + s] = val;
      }
    }
  }
}

// ---------------- flash attention (32x32x16 MFMA) ----------------
// grid (bh=32, qtile=16), block 256 (4 waves x 32 q = 128 q/block). KV tile 64, dbuf.
// Per wave: QK = 2 tblk x 4 kstep MFMAs (A=K from LDS, swizzled); PV = 2 dh x 4 j
// (A=V from LDS, tau-permuted t-layout so PV B-operand = QK C-layout regs directly).
// tau(j,hi,e) = 8*(2j+(e>>2)) + 4*hi + (e&3);  B-frag j == s-regs [8j..8j+7]. P never
// touches LDS. C/D 32x32 layout: col=lane&31(q), row=(r&3)+8*(r>>2)+4*(lane>>5).
// LDS 32KB: K0 [0,8192) K1 [8192,16384) V0 [16384,24576) V1 [24576,32768).

#define MFMA32(A, B, C) __builtin_amdgcn_mfma_f32_32x32x16_bf16(A, B, C, 0, 0, 0)

#define TILE_BODY(KOFF, MA, MB)                                                    \
  {                                                                                \
    f32x16 sA, sB;                                                                 \
    __builtin_amdgcn_s_setprio(1);                                                 \
    {                                                                              \
      const char* kb0 = ldsb + (KOFF) + Kb;                                        \
      sA = MFMA32(*(const bf16x8*)(kb0 + o0), qf0, MA);                            \
      sB = MFMA32(*(const bf16x8*)(kb0 + 4096 + o0), qf0, MB);                     \
      sA = MFMA32(*(const bf16x8*)(kb0 + o1), qf1, sA);                            \
      sB = MFMA32(*(const bf16x8*)(kb0 + 4096 + o1), qf1, sB);                     \
      sA = MFMA32(*(const bf16x8*)(kb0 + o2), qf2, sA);                            \
      sB = MFMA32(*(const bf16x8*)(kb0 + 4096 + o2), qf2, sB);                     \
      sA = MFMA32(*(const bf16x8*)(kb0 + o3), qf3, sA);                            \
      sB = MFMA32(*(const bf16x8*)(kb0 + 4096 + o3), qf3, sB);                     \
    }                                                                              \
    __builtin_amdgcn_s_setprio(0);                                                 \
    float pm = fmaxf(                                                              \
        fmaxf(fmaxf(fmaxf(fmaxf(sA[0], sA[1]), fmaxf(sA[2], sA[3])),               \
                    fmaxf(fmaxf(sA[4], sA[5]), fmaxf(sA[6], sA[7]))),              \
              fmaxf(fmaxf(fmaxf(sA[8], sA[9]), fmaxf(sA[10], sA[11])),             \
                    fmaxf(fmaxf(sA[12], sA[13]), fmaxf(sA[14], sA[15])))),         \
        fmaxf(fmaxf(fmaxf(fmaxf(sB[0], sB[1]), fmaxf(sB[2], sB[3])),               \
                    fmaxf(fmaxf(sB[4], sB[5]), fmaxf(sB[6], sB[7]))),              \
              fmaxf(fmaxf(fmaxf(sB[8], sB[9]), fmaxf(sB[10], sB[11])),             \
                    fmaxf(fmaxf(sB[12], sB[13]), fmaxf(sB[14], sB[15])))));        \
    /* speculative exp with current m; shfl max-reduce overlaps */                 \
    _Pragma("unroll")                                                              \
    for (int e_ = 0; e_ < 16; e_++) { sA[e_] = EXP2F(sA[e_] - m); }                \
    _Pragma("unroll")                                                              \
    for (int e_ = 0; e_ < 16; e_++) { sB[e_] = EXP2F(sB[e_] - m); }                \
    float ps = (((sA[0] + sA[1]) + (sA[2] + sA[3])) +                              \
                ((sA[4] + sA[5]) + (sA[6] + sA[7]))) +                             \
               (((sA[8] + sA[9]) + (sA[10] + sA[11])) +                            \
                ((sA[12] + sA[13]) + (sA[14] + sA[15]))) +                         \
               (((sB[0] + sB[1]) + (sB[2] + sB[3])) +                              \
                ((sB[4] + sB[5]) + (sB[6] + sB[7]))) +                             \
               (((sB[8] + sB[9]) + (sB[10] + sB[11])) +                            \
                ((sB[12] + sB[13]) + (sB[14] + sB[15])));                          \
    pm = fmaxf(pm, __shfl_xor(pm, 32));                                            \
    if (__any(pm > m + 8.0f)) {  /* rare: fix speculation exactly */               \
      const float mn = fmaxf(m, pm);                                               \
      const float al = EXP2F(m - mn);                                              \
      m = mn; lsum *= al; ps *= al;                                                \
      sA *= al; sB *= al; ctx0 *= al; ctx1 *= al;                                  \
    }                                                                              \
    lsum += ps;                                                                    \
    bf16x8 pa0, pa1, pa2, pa3;                                                     \
    _Pragma("unroll")                                                              \
    for (int e_ = 0; e_ < 8; e_++) {                                               \
      pa0[e_] = (__bf16)sA[e_]; pa1[e_] = (__bf16)sA[8 + e_];                      \
      pa2[e_] = (__bf16)sB[e_]; pa3[e_] = (__bf16)sB[8 + e_];                      \
    }                                                                              \
    {                                                                              \
      const char* vb0 = ldsb + 16384 + (KOFF) + Vb;                                \
      __builtin_amdgcn_s_setprio(1);                                               \
      ctx0 = MFMA32(*(const bf16x8*)(vb0 + 0), pa0, ctx0);                         \
      ctx1 = MFMA32(*(const bf16x8*)(vb0 + 1024), pa0, ctx1);                      \
      ctx0 = MFMA32(*(const bf16x8*)(vb0 + 2048), pa1, ctx0);                      \
      ctx1 = MFMA32(*(const bf16x8*)(vb0 + 3072), pa1, ctx1);                      \
      ctx0 = MFMA32(*(const bf16x8*)(vb0 + 4096), pa2, ctx0);                      \
      ctx1 = MFMA32(*(const bf16x8*)(vb0 + 5120), pa2, ctx1);                      \
      ctx0 = MFMA32(*(const bf16x8*)(vb0 + 6144), pa3, ctx0);                      \
      ctx1 = MFMA32(*(const bf16x8*)(vb0 + 7168), pa3, ctx1);                      \
      __builtin_amdgcn_s_setprio(0);                                               \
    }                                                                              \
  }

__global__ __launch_bounds__(256, 2) void attn_fwd(
    const u16* __restrict__ qbf, const u16* __restrict__ kbf, const u16* __restrict__ vtbf,
    const float* __restrict__ mask, u16* __restrict__ ctxout) {
  __shared__ u16 lds[16384];  // 32 KB
  char* ldsb = (char*)lds;
  const int tid = threadIdx.x, lane = tid & 63, w = tid >> 6;
  const int q32 = lane & 31, hi = lane >> 5;
  const int bh = blockIdx.x, qt = blockIdx.y;
  const int qbase = qt * 128;
  const size_t hbase = (size_t)bh * 2048 * 64;
  const int qglob = qbase + w * 32 + q32;

  // K read addressing (swizzled rows, loop-invariant)
  const int x = (q32 & 7) << 4;
  const int Kb = q32 * 128;
  const int o0 = (0 + hi * 16) ^ x;
  const int o1 = (32 + hi * 16) ^ x;
  const int o2 = (64 + hi * 16) ^ x;
  const int o3 = (96 + hi * 16) ^ x;
  // V read base (tau-layout; lane-sequential, conflict-free)
  const int Vb = hi * 512 + q32 * 16;
  // staging indices
  const int srow = tid >> 3, Ac = tid & 7;
  const int S0 = srow * 128 + ((Ac * 16) ^ ((srow & 7) << 4));
  const int S1 = S0 + 4096;
  const int jv = Ac >> 1, epos = (Ac & 1) * 8;
  const int VW0 = jv * 2048 + srow * 16 + epos;         // d=srow (dh=0), hi=0 piece
  const int VW1 = jv * 2048 + 1024 + srow * 16 + epos;  // d=srow+32 (dh=1)

  // Q fragments (B-operand; pre-scaled by 0.125*log2e in qkv epilogue)
  const u16* qrow = qbf + hbase + (size_t)qglob * 64 + hi * 8;
  bf16x8 qf0 = *(const bf16x8*)(qrow + 0);
  bf16x8 qf1 = *(const bf16x8*)(qrow + 16);
  bf16x8 qf2 = *(const bf16x8*)(qrow + 32);
  bf16x8 qf3 = *(const bf16x8*)(qrow + 48);

  // prologue: tile 0 -> buf0, tile 1 -> regs
  float4 kr0, kr1, vr0, vr1;
  kr0 = *(const float4*)&kbf[hbase + (size_t)srow * 64 + Ac * 8];
  kr1 = *(const float4*)&kbf[hbase + (size_t)(32 + srow) * 64 + Ac * 8];
  vr0 = *(const float4*)&vtbf[hbase + (size_t)srow * 2048 + Ac * 8];
  vr1 = *(const float4*)&vtbf[hbase + (size_t)(32 + srow) * 2048 + Ac * 8];
  *(float4*)(ldsb + S0) = kr0;
  *(float4*)(ldsb + S1) = kr1;
  *(float2*)(ldsb + 16384 + VW0) = make_float2(vr0.x, vr0.y);
  *(float2*)(ldsb + 16384 + VW0 + 512) = make_float2(vr0.z, vr0.w);
  *(float2*)(ldsb + 16384 + VW1) = make_float2(vr1.x, vr1.y);
  *(float2*)(ldsb + 16384 + VW1 + 512) = make_float2(vr1.z, vr1.w);
  kr0 = *(const float4*)&kbf[hbase + (size_t)(64 + srow) * 64 + Ac * 8];
  kr1 = *(const float4*)&kbf[hbase + (size_t)(96 + srow) * 64 + Ac * 8];
  vr0 = *(const float4*)&vtbf[hbase + (size_t)srow * 2048 + 64 + Ac * 8];
  vr1 = *(const float4*)&vtbf[hbase + (size_t)(32 + srow) * 2048 + 64 + Ac * 8];

  // global stream pointers (tile 2 onward)
  const u16* kp = kbf + hbase + (size_t)(128 + srow) * 64 + Ac * 8;
  const u16* vp = vtbf + hbase + (size_t)srow * 2048 + 128 + Ac * 8;
  const float* mpp = mask + (size_t)qglob * 2048 + hi * 4;

  f32x16 mcA, mcB, mdA, mdB;
#pragma unroll
  for (int jq = 0; jq < 4; jq++) {
    ((f32x4*)&mcA)[jq] = (*(const f32x4*)(mpp + jq * 8)) * LOG2E;
    ((f32x4*)&mcB)[jq] = (*(const f32x4*)(mpp + 32 + jq * 8)) * LOG2E;
  }

  float m = 0.f, lsum = 0.f;  // m=0 init safe: defer-max picks up
  f32x16 ctx0 = (f32x16)(0.f), ctx1 = (f32x16)(0.f);

  __syncthreads();

  for (int i = 0; i < 16; ++i) {
    // ---- even tile 2i (K at 0, V at 16384) ----
    *(float4*)(ldsb + 8192 + S0) = kr0;   // stage tile 2i+1 -> buf1
    *(float4*)(ldsb + 8192 + S1) = kr1;
    *(float2*)(ldsb + 24576 + VW0) = make_float2(vr0.x, vr0.y);
    *(float2*)(ldsb + 24576 + VW0 + 512) = make_float2(vr0.z, vr0.w);
    *(float2*)(ldsb + 24576 + VW1) = make_float2(vr1.x, vr1.y);
    *(float2*)(ldsb + 24576 + VW1 + 512) = make_float2(vr1.z, vr1.w);
    if (i < 15) {                          // load tile 2i+2
      kr0 = *(const float4*)kp;
      kr1 = *(const float4*)(kp + 2048);
      vr0 = *(const float4*)vp;
      vr1 = *(const float4*)(vp + 65536);
      kp += 4096; vp += 64;
    }
#pragma unroll
    for (int jq = 0; jq < 4; jq++) {       // mask tile 2i+1
      ((f32x4*)&mdA)[jq] = (*(const f32x4*)(mpp + 64 + jq * 8)) * LOG2E;
      ((f32x4*)&mdB)[jq] = (*(const f32x4*)(mpp + 96 + jq * 8)) * LOG2E;
    }
    TILE_BODY(0, mcA, mcB)
    __syncthreads();

    // ---- odd tile 2i+1 (K at 8192, V at 24576) ----
    if (i < 15) {
      *(float4*)(ldsb + S0) = kr0;         // stage tile 2i+2 -> buf0
      *(float4*)(ldsb + S1) = kr1;
      *(float2*)(ldsb + 16384 + VW0) = make_float2(vr0.x, vr0.y);
      *(float2*)(ldsb + 16384 + VW0 + 512) = make_float2(vr0.z, vr0.w);
      *(float2*)(ldsb + 16384 + VW1) = make_float2(vr1.x, vr1.y);
      *(float2*)(ldsb + 16384 + VW1 + 512) = make_float2(vr1.z, vr1.w);
      kr0 = *(const float4*)kp;            // load tile 2i+3
      kr1 = *(const float4*)(kp + 2048);
      vr0 = *(const float4*)vp;
      vr1 = *(const float4*)(vp + 65536);
      kp += 4096; vp += 64;
#pragma unroll
      for (int jq = 0; jq < 4; jq++) {     // mask tile 2i+2
        ((f32x4*)&mcA)[jq] = (*(const f32x4*)(mpp + 128 + jq * 8)) * LOG2E;
        ((f32x4*)&mcB)[jq] = (*(const f32x4*)(mpp + 160 + jq * 8)) * LOG2E;
      }
    }
    TILE_BODY(8192, mdA, mdB)
    mpp += 128;
    __syncthreads();
  }

  // finalize: row spans (lane, lane+32) -> one shfl; per-lane partial lsum valid
  // because m/al history is row-uniform (pm reduced every tile).
  lsum += __shfl_xor(lsum, 32);
  const float inv = 1.0f / lsum;
  const int b = bh >> 4, h = bh & 15;
  u16* orow = ctxout + (size_t)(b * 2048 + qglob) * 1024 + h * 64;
#pragma unroll
  for (int jq = 0; jq < 4; jq++) {
    bf16x4 o0, o1;
#pragma unroll
    for (int rr = 0; rr < 4; rr++) {
      o0[rr] = (__bf16)(ctx0[4 * jq + rr] * inv);
      o1[rr] = (__bf16)(ctx1[4 * jq + rr] * inv);
    }
    *(bf16x4*)&orow[jq * 8 + hi * 4] = o0;
    *(bf16x4*)&orow[32 + jq * 8 + hi * 4] = o1;
  }
}

// ---------------- output projection GEMM ----------------
__global__ __launch_bounds__(256, 2) void proj_gemm(
    const u16* __restrict__ ctx, const u16* __restrict__ wbf,
    const float* __restrict__ bias, float* __restrict__ out) {
  __shared__ u16 Al[128 * 32];
  __shared__ u16 Bl[128 * 32];
  const int tid = threadIdx.x;
  const int lane = tid & 63;
  const int w = tid >> 6;
  const int wr = w >> 1, wc = w & 1;
  const int nb = blockIdx.x, mb = blockIdx.y;
  const int row0 = mb * 128;
  const int ncol0 = nb * 128;
  const u16* Bw = wbf + (size_t)ncol0 * 1024;

  f32x4 acc[4][4];
  f32x4 zero = {0.f, 0.f, 0.f, 0.f};
#pragma unroll
  for (int i = 0; i < 4; i++)
#pragma unroll
    for (int j = 0; j < 4; j++) acc[i][j] = zero;

  const int srow = w * 16 + (lane >> 2);
  const int scol = (lane & 3) * 8;

  for (int k0 = 0; k0 < 1024; k0 += 32) {
#pragma unroll
    for (int p = 0; p < 2; p++) {
      const u16* ga = ctx + (size_t)(row0 + p * 64 + srow) * 1024 + k0 + scol;
      GLL16(ga, &Al[(p * 64 + w * 16) * 32]);
      const u16* gb = Bw + (size_t)(p * 64 + srow) * 1024 + k0 + scol;
      GLL16(gb, &Bl[(p * 64 + w * 16) * 32]);
    }
    __syncthreads();
    bf16x8 af[4], bfr[4];
#pragma unroll
    for (int mi = 0; mi < 4; mi++)
      af[mi] = *(const bf16x8*)&Al[(wr * 64 + mi * 16 + (lane & 15)) * 32 + (lane >> 4) * 8];
#pragma unroll
    for (int ni = 0; ni < 4; ni++)
      bfr[ni] = *(const bf16x8*)&Bl[(wc * 64 + ni * 16 + (lane & 15)) * 32 + (lane >> 4) * 8];
#pragma unroll
    for (int mi = 0; mi < 4; mi++)
#pragma unroll
      for (int ni = 0; ni < 4; ni++)
        acc[mi][ni] = __builtin_amdgcn_mfma_f32_16x16x32_bf16(af[mi], bfr[ni], acc[mi][ni], 0, 0, 0);
    __syncthreads();
  }

#pragma unroll
  for (int mi = 0; mi < 4; mi++) {
    const int rb = row0 + wr * 64 + mi * 16 + (lane >> 4) * 4;
#pragma unroll
    for (int ni = 0; ni < 4; ni++) {
      const int c = ncol0 + wc * 64 + ni * 16 + (lane & 15);
      const float bs = bias[c];
#pragma unroll
      for (int r = 0; r < 4; r++)
        out[(size_t)(rb + r) * 1024 + c] = acc[mi][ni][r] + bs;
    }
  }
}

// ---------------- launch ----------------
extern "C" void kernel_launch(void* const* d_in, const int* in_sizes, int n_in,
                              void* d_out, int out_size, void* d_ws, size_t ws_size,
                              hipStream_t stream) {
  const float* query = (const float*)d_in[0];
  const float* key   = (const float*)d_in[1];
  const float* value = (const float*)d_in[2];
  const float* qkvw  = (const float*)d_in[3];
  const float* qkvb  = (const float*)d_in[4];
  const float* projw = (const float*)d_in[5];
  const float* projb = (const float*)d_in[6];
  const float* mask  = (const float*)d_in[7];

  char* ws = (char*)d_ws;
  u16* xq    = (u16*)(ws + 0);          // 8 MiB  (later: ctx)
  u16* xk    = (u16*)(ws + 8388608);    // 8 MiB
  u16* xv    = (u16*)(ws + 16777216);   // 8 MiB
  u16* wqkv  = (u16*)(ws + 25165824);   // 6 MiB
  u16* wproj = (u16*)(ws + 31457280);   // 2 MiB
  u16* qb    = (u16*)(ws + 33554432);   // 8 MiB  [B,H,S,D] (pre-scaled)
  u16* kb    = (u16*)(ws + 41943040);   // 8 MiB  [B,H,S,D]
  u16* vt    = (u16*)(ws + 50331648);   // 8 MiB  [B,H,D,S]
  u16* cx    = xq;                      // ctx bf16, aliases xq

  cvt_all<<<16384, 256, 0, stream>>>(query, key, value, qkvw, projw, xq, xk, xv, wqkv, wproj);
  qkv_gemm<<<dim3(24, 32), 256, 0, stream>>>(xq, xk, xv, wqkv, qkvb, qb, kb, vt);
  attn_fwd<<<dim3(32, 16), 256, 0, stream>>>(qb, kb, vt, mask, cx);
  proj_gemm<<<dim3(8, 32), 256, 0, stream>>>(cx, wproj, projb, (float*)d_out);
}